// Round 9
// baseline (3092.176 us; speedup 1.0000x reference)
//
#include <hip/hip_runtime.h>
#include <hip/hip_fp16.h>

namespace {

constexpr int kS = 1024;   // SEQ
constexpr int kI = 64;     // INPUT_SIZE
constexpr int kH = 128;    // HIDDEN

typedef _Float16 f16x8 __attribute__((ext_vector_type(8)));
typedef float    f32x4 __attribute__((ext_vector_type(4)));

#define MFMA16(a, b, c) __builtin_amdgcn_mfma_f32_16x16x32_f16((a), (b), (c), 0, 0, 0)

__device__ __forceinline__ float rcpf(float x) {
#if __has_builtin(__builtin_amdgcn_rcpf)
  return __builtin_amdgcn_rcpf(x);
#else
  return 1.0f / x;
#endif
}
__device__ __forceinline__ float sigf(float x)  { return rcpf(1.0f + __expf(-x)); }
__device__ __forceinline__ float tanhff(float x){ return 1.0f - 2.0f * rcpf(1.0f + __expf(2.0f * x)); }

template <int P>
__device__ __forceinline__ void prio() {
#if __has_builtin(__builtin_amdgcn_s_setprio)
  __builtin_amdgcn_s_setprio(P);   // literal constant via template param
#endif
}

// A fragment: lane (q, j) holds W[row=base+j][k0+q*8 .. +7]. A and B use the
// same k-chunk packing so any HW k-permutation cancels; only the C/D mapping
// (col=lane&15, row=(lane>>4)*4+reg) is load-bearing.
__device__ __forceinline__ f16x8 afrag(const float* __restrict__ W, int row,
                                       int k0, int ld) {
  const float4* p = reinterpret_cast<const float4*>(W + (size_t)row * ld + k0);
  const float4 u = p[0], v = p[1];
  f16x8 a;
  a[0] = (_Float16)u.x; a[1] = (_Float16)u.y; a[2] = (_Float16)u.z; a[3] = (_Float16)u.w;
  a[4] = (_Float16)v.x; a[5] = (_Float16)v.y; a[6] = (_Float16)v.z; a[7] = (_Float16)v.w;
  return a;
}

// ---------------- K1: layer-1 via MFMA, 1 chain/block ----------------
// 512 blocks x 1024 thr (16 waves) -> 2 blocks/CU: one block's MFMA hides the
// other's activation/barrier stalls. Wave w owns gate rows [32w,32w+32) as
// 2 M-tiles x 6 K-tiles; A frags = 48 VGPR. B col 0 = the chain; cols 1..15
// pad (read chunk-0 broadcast, result discarded).
__global__ __launch_bounds__(1024) void lstm_l1(
    const float* __restrict__ x, const float* __restrict__ Wx1,
    const float* __restrict__ bx1, const float* __restrict__ Wh1,
    const float* __restrict__ bh1, _Float16* __restrict__ h1out)
{
  const int tid = threadIdx.x;
  const int b   = blockIdx.x;
  const int w   = tid >> 6;           // wave 0..15
  const int q   = (tid >> 4) & 3;     // k-group
  const int n   = tid & 15;           // B/D col
  const bool real = (n == 0);

  __shared__ __align__(16) _Float16 xB[8][8][8];    // [t][kchunk][e] 1 KiB
  __shared__ __align__(16) _Float16 hB[2][16][8];   // [par][kchunk][e] 512 B
  __shared__ float gbuf[512];                       // gate preacts (col 0)

  f16x8 A[2][6];
  {
    const int rb = w * 32 + (tid & 15);
#pragma unroll
    for (int s = 0; s < 2; ++s) {
      const int row = rb + s * 16;
      A[s][0] = afrag(Wx1, row, q * 8,      kI);
      A[s][1] = afrag(Wx1, row, 32 + q * 8, kI);
#pragma unroll
      for (int kt = 0; kt < 4; ++kt)
        A[s][2 + kt] = afrag(Wh1, row, kt * 32 + q * 8, kH);
    }
  }

  float bI = 0.f, bF = 0.f, bG = 0.f, bO = 0.f, cst = 0.f;
  if (tid < 128) {
    bI = bx1[tid]       + bh1[tid];
    bF = bx1[tid + 128] + bh1[tid + 128];
    bG = bx1[tid + 256] + bh1[tid + 256];
    bO = bx1[tid + 384] + bh1[tid + 384];
    reinterpret_cast<_Float16*>(hB)[tid] = (_Float16)0.f;   // hB[0] = 0
  }

  const int boff = real ? (q * 16) : 0;   // pad lanes: broadcast chunk 0

  for (int t0 = 0; t0 < kS; t0 += 8) {
    if (tid < 512) {   // stage x[b][t0..t0+7][:] -> fp16 B layout
      const int st = tid >> 6, sk = tid & 63;
      xB[st][sk >> 3][sk & 7] =
          (_Float16)x[((size_t)b * kS + (size_t)(t0 + st)) * kI + sk];
    }
    __syncthreads();

    for (int dt = 0; dt < 8; ++dt) {
      const int t = t0 + dt;
      const char* xb = reinterpret_cast<const char*>(&xB[dt][0][0]);
      const char* hb = reinterpret_cast<const char*>(&hB[t & 1][0][0]);
      const f16x8 bf0 = *reinterpret_cast<const f16x8*>(xb + boff);
      const f16x8 bf1 = *reinterpret_cast<const f16x8*>(xb + 64  + boff);
      const f16x8 bf2 = *reinterpret_cast<const f16x8*>(hb + boff);
      const f16x8 bf3 = *reinterpret_cast<const f16x8*>(hb + 64  + boff);
      const f16x8 bf4 = *reinterpret_cast<const f16x8*>(hb + 128 + boff);
      const f16x8 bf5 = *reinterpret_cast<const f16x8*>(hb + 192 + boff);

      f32x4 d0 = {0.f, 0.f, 0.f, 0.f}, d1 = {0.f, 0.f, 0.f, 0.f};
      prio<1>();
      d0 = MFMA16(A[0][0], bf0, d0);  d1 = MFMA16(A[1][0], bf0, d1);
      d0 = MFMA16(A[0][1], bf1, d0);  d1 = MFMA16(A[1][1], bf1, d1);
      d0 = MFMA16(A[0][2], bf2, d0);  d1 = MFMA16(A[1][2], bf2, d1);
      d0 = MFMA16(A[0][3], bf3, d0);  d1 = MFMA16(A[1][3], bf3, d1);
      d0 = MFMA16(A[0][4], bf4, d0);  d1 = MFMA16(A[1][4], bf4, d1);
      d0 = MFMA16(A[0][5], bf5, d0);  d1 = MFMA16(A[1][5], bf5, d1);
      prio<0>();

      if (real) {   // D rows 32w+16s+4q..+3, col 0
        *reinterpret_cast<f32x4*>(&gbuf[w * 32 + q * 4])      = d0;
        *reinterpret_cast<f32x4*>(&gbuf[w * 32 + 16 + q * 4]) = d1;
      }
      __syncthreads();

      if (tid < 128) {
        const float gi = gbuf[tid]       + bI;
        const float gf = gbuf[tid + 128] + bF;
        const float gg = gbuf[tid + 256] + bG;
        const float go = gbuf[tid + 384] + bO;
        cst = sigf(gf) * cst + sigf(gi) * tanhff(gg);
        const float h = sigf(go) * tanhff(cst);
        hB[(t + 1) & 1][tid >> 3][tid & 7] = (_Float16)h;
        h1out[((size_t)b * kS + (size_t)t) * kH + tid] = (_Float16)h;
      }
      __syncthreads();
    }
  }
}

// ---------------- K2: layer-2 via MFMA + head, 1 chain/block ----------------
// K = 256 = [h1(t); h2(t-1)] -> 8 K-tiles; A = 64 VGPR (the 2-blocks/CU
// boundary -- keep it there).
__global__ __launch_bounds__(1024) void lstm_l2(
    const _Float16* __restrict__ h1in,
    const float* __restrict__ Wx2, const float* __restrict__ bx2,
    const float* __restrict__ Wh2, const float* __restrict__ bh2,
    const float* __restrict__ Wc,  const float* __restrict__ bc,
    float* __restrict__ out)
{
  const int tid = threadIdx.x;
  const int b   = blockIdx.x;
  const int w   = tid >> 6;
  const int q   = (tid >> 4) & 3;
  const int n   = tid & 15;
  const bool real = (n == 0);

  __shared__ __align__(16) _Float16 h1B[8][16][8];   // [t][kchunk][e] 2 KiB
  __shared__ __align__(16) _Float16 h2B[2][16][8];   // 512 B
  __shared__ float gbuf[512];
  __shared__ float hfin[128];

  f16x8 A[2][8];
  {
    const int rb = w * 32 + (tid & 15);
#pragma unroll
    for (int s = 0; s < 2; ++s) {
      const int row = rb + s * 16;
#pragma unroll
      for (int kt = 0; kt < 4; ++kt) {
        A[s][kt]     = afrag(Wx2, row, kt * 32 + q * 8, kH);
        A[s][4 + kt] = afrag(Wh2, row, kt * 32 + q * 8, kH);
      }
    }
  }

  float bI = 0.f, bF = 0.f, bG = 0.f, bO = 0.f, cst = 0.f;
  if (tid < 128) {
    bI = bx2[tid]       + bh2[tid];
    bF = bx2[tid + 128] + bh2[tid + 128];
    bG = bx2[tid + 256] + bh2[tid + 256];
    bO = bx2[tid + 384] + bh2[tid + 384];
    reinterpret_cast<_Float16*>(h2B)[tid] = (_Float16)0.f;   // h2B[0] = 0
  }

  const int boff = real ? (q * 16) : 0;

  for (int t0 = 0; t0 < kS; t0 += 8) {
    {  // stage h1[b][t0..t0+7][:] (1024 fp16, 1 per thread)
      const int st = tid >> 7, sk = tid & 127;
      h1B[st][sk >> 3][sk & 7] =
          h1in[((size_t)b * kS + (size_t)(t0 + st)) * kH + sk];
    }
    __syncthreads();

    for (int dt = 0; dt < 8; ++dt) {
      const int t = t0 + dt;
      const char* xb = reinterpret_cast<const char*>(&h1B[dt][0][0]);
      const char* hb = reinterpret_cast<const char*>(&h2B[t & 1][0][0]);

      f32x4 d0 = {0.f, 0.f, 0.f, 0.f}, d1 = {0.f, 0.f, 0.f, 0.f};
      {
        const f16x8 bf0 = *reinterpret_cast<const f16x8*>(xb + boff);
        const f16x8 bf1 = *reinterpret_cast<const f16x8*>(xb + 64  + boff);
        const f16x8 bf2 = *reinterpret_cast<const f16x8*>(xb + 128 + boff);
        const f16x8 bf3 = *reinterpret_cast<const f16x8*>(xb + 192 + boff);
        prio<1>();
        d0 = MFMA16(A[0][0], bf0, d0);  d1 = MFMA16(A[1][0], bf0, d1);
        d0 = MFMA16(A[0][1], bf1, d0);  d1 = MFMA16(A[1][1], bf1, d1);
        d0 = MFMA16(A[0][2], bf2, d0);  d1 = MFMA16(A[1][2], bf2, d1);
        d0 = MFMA16(A[0][3], bf3, d0);  d1 = MFMA16(A[1][3], bf3, d1);
        prio<0>();
      }
#if __has_builtin(__builtin_amdgcn_sched_barrier)
      __builtin_amdgcn_sched_barrier(0);   // cap B-frag live range (VGPR budget)
#endif
      {
        const f16x8 bf4 = *reinterpret_cast<const f16x8*>(hb + boff);
        const f16x8 bf5 = *reinterpret_cast<const f16x8*>(hb + 64  + boff);
        const f16x8 bf6 = *reinterpret_cast<const f16x8*>(hb + 128 + boff);
        const f16x8 bf7 = *reinterpret_cast<const f16x8*>(hb + 192 + boff);
        prio<1>();
        d0 = MFMA16(A[0][4], bf4, d0);  d1 = MFMA16(A[1][4], bf4, d1);
        d0 = MFMA16(A[0][5], bf5, d0);  d1 = MFMA16(A[1][5], bf5, d1);
        d0 = MFMA16(A[0][6], bf6, d0);  d1 = MFMA16(A[1][6], bf6, d1);
        d0 = MFMA16(A[0][7], bf7, d0);  d1 = MFMA16(A[1][7], bf7, d1);
        prio<0>();
      }

      if (real) {
        *reinterpret_cast<f32x4*>(&gbuf[w * 32 + q * 4])      = d0;
        *reinterpret_cast<f32x4*>(&gbuf[w * 32 + 16 + q * 4]) = d1;
      }
      __syncthreads();

      if (tid < 128) {
        const float gi = gbuf[tid]       + bI;
        const float gf = gbuf[tid + 128] + bF;
        const float gg = gbuf[tid + 256] + bG;
        const float go = gbuf[tid + 384] + bO;
        cst = sigf(gf) * cst + sigf(gi) * tanhff(gg);
        const float h = sigf(go) * tanhff(cst);
        h2B[(t + 1) & 1][tid >> 3][tid & 7] = (_Float16)h;
        if (t == kS - 1) hfin[tid] = h;
      }
      __syncthreads();
    }
  }

  // classifier head: logits[b, m] = Wc[m,:] . h2fin + bc[m]
  if (tid < 4) {
    const float* wr = Wc + (size_t)tid * kH;
    float s0 = 0.f, s1 = 0.f, s2 = 0.f, s3 = 0.f;
#pragma unroll
    for (int j = 0; j < kH; j += 4) {
      s0 = fmaf(wr[j],     hfin[j],     s0);
      s1 = fmaf(wr[j + 1], hfin[j + 1], s1);
      s2 = fmaf(wr[j + 2], hfin[j + 2], s2);
      s3 = fmaf(wr[j + 3], hfin[j + 3], s3);
    }
    out[(size_t)b * 4 + tid] = bc[tid] + ((s0 + s1) + (s2 + s3));
  }
}

} // namespace

extern "C" void kernel_launch(void* const* d_in, const int* in_sizes, int n_in,
                              void* d_out, int out_size, void* d_ws, size_t ws_size,
                              hipStream_t stream) {
  const float* x   = (const float*)d_in[0];
  const float* Wx1 = (const float*)d_in[1];
  const float* bx1 = (const float*)d_in[2];
  const float* Wh1 = (const float*)d_in[3];
  const float* bh1 = (const float*)d_in[4];
  const float* Wx2 = (const float*)d_in[5];
  const float* bx2 = (const float*)d_in[6];
  const float* Wh2 = (const float*)d_in[7];
  const float* bh2 = (const float*)d_in[8];
  const float* Wc  = (const float*)d_in[9];
  const float* bc  = (const float*)d_in[10];

  _Float16* h1 = (_Float16*)d_ws;   // 512*1024*128 fp16 = 128 MiB layer-1 stream

  hipLaunchKernelGGL(lstm_l1, dim3(512), dim3(1024), 0, stream,
                     x, Wx1, bx1, Wh1, bh1, h1);
  hipLaunchKernelGGL(lstm_l2, dim3(512), dim3(1024), 0, stream,
                     h1, Wx2, bx2, Wh2, bh2, Wc, bc, (float*)d_out);
}

// Round 10
// 1536.605 us; speedup vs baseline: 2.0123x; 2.0123x over previous
//
#include <hip/hip_runtime.h>
#include <hip/hip_fp16.h>

namespace {

constexpr int kS = 1024;   // SEQ
constexpr int kI = 64;     // INPUT_SIZE
constexpr int kH = 128;    // HIDDEN

typedef _Float16 f16x8 __attribute__((ext_vector_type(8)));
typedef float    f32x4 __attribute__((ext_vector_type(4)));

#define MFMA16(a, b, c) __builtin_amdgcn_mfma_f32_16x16x32_f16((a), (b), (c), 0, 0, 0)

__device__ __forceinline__ float rcpf(float x) {
#if __has_builtin(__builtin_amdgcn_rcpf)
  return __builtin_amdgcn_rcpf(x);
#else
  return 1.0f / x;
#endif
}
__device__ __forceinline__ float sigf(float x)  { return rcpf(1.0f + __expf(-x)); }
__device__ __forceinline__ float tanhff(float x){ return 1.0f - 2.0f * rcpf(1.0f + __expf(2.0f * x)); }

template <int P>
__device__ __forceinline__ void prio() {
#if __has_builtin(__builtin_amdgcn_s_setprio)
  __builtin_amdgcn_s_setprio(P);
#endif
}

__device__ __forceinline__ unsigned packf2(float lo, float hi) {
  _Float16 a = (_Float16)lo, b = (_Float16)hi;
  unsigned short ua = __builtin_bit_cast(unsigned short, a);
  unsigned short ub = __builtin_bit_cast(unsigned short, b);
  return (unsigned)ua | ((unsigned)ub << 16);
}

// A fragment: lane (q, j=lane&15) holds W[row=base+j][k0 .. k0+7]. A and B use
// the same k-chunk packing so any HW k-permutation cancels; the C/D mapping
// (col=lane&15, row=(lane>>4)*4+reg) is the only load-bearing layout.
__device__ __forceinline__ f16x8 afrag(const float* __restrict__ W, int row,
                                       int k0, int ld) {
  const float4* p = reinterpret_cast<const float4*>(W + (size_t)row * ld + k0);
  const float4 u = p[0], v = p[1];
  f16x8 a;
  a[0] = (_Float16)u.x; a[1] = (_Float16)u.y; a[2] = (_Float16)u.z; a[3] = (_Float16)u.w;
  a[4] = (_Float16)v.x; a[5] = (_Float16)v.y; a[6] = (_Float16)v.z; a[7] = (_Float16)v.w;
  return a;
}

// ---------------- K1: layer-1, batched-x GEMM + recurrent MFMA ----------------
// 256 blocks x 1024 thr (16 waves), chains b0,b0+1. Per 8-step tile: one real
// GEMM (N=16 = 8 steps x 2 chains) computes Wx1.x into xg; per step only the
// 4-K-tile Wh1 part runs (4 ds_read_b128/wave/step instead of 6).
__global__ __launch_bounds__(1024) void lstm_l1(
    const float* __restrict__ x, const float* __restrict__ Wx1,
    const float* __restrict__ bx1, const float* __restrict__ Wh1,
    const float* __restrict__ bh1, _Float16* __restrict__ h1out)
{
  const int tid  = threadIdx.x;
  const int b0   = blockIdx.x * 2;
  const int w    = tid >> 6;
  const int lane = tid & 63;
  const int q    = lane >> 4;          // k-group 0..3
  const int n    = lane & 15;          // B/D col

  __shared__ __align__(16) _Float16 xF[8][16][8];      // [kc][col][e] 2 KiB
  __shared__ __align__(16) _Float16 h1B[2][2][16][8];  // [par][c][kc][e] 1 KiB
  __shared__ float xg[512][17];                        // 34 KiB x-projection
  __shared__ float gbuf[2][512];                       // 4 KiB recurrent preacts

  f16x8 Ax[2][2], Ah[2][4];            // 24 frags? no: 4 + 8 = 12 frags, 48 VGPR
  {
    const int rb = w * 32 + n;
#pragma unroll
    for (int s = 0; s < 2; ++s) {
      const int row = rb + s * 16;
#pragma unroll
      for (int kt = 0; kt < 2; ++kt) Ax[s][kt] = afrag(Wx1, row, kt * 32 + q * 8, kI);
#pragma unroll
      for (int kt = 0; kt < 4; ++kt) Ah[s][kt] = afrag(Wh1, row, kt * 32 + q * 8, kH);
    }
  }

  float bI = 0.f, bF = 0.f, bG = 0.f, bO = 0.f, cst = 0.f;
  if (tid < 256) {
    const int j = tid & 127;
    bI = bx1[j]       + bh1[j];
    bF = bx1[j + 128] + bh1[j + 128];
    bG = bx1[j + 256] + bh1[j + 256];
    bO = bx1[j + 384] + bh1[j + 384];
    reinterpret_cast<_Float16*>(&h1B[1][0][0][0])[tid] = (_Float16)0.f;  // h(-1)=0
  }

  const int csel  = (n < 2) ? n : 0;   // pad cols broadcast chain 0
  const char* h1base = reinterpret_cast<const char*>(&h1B[0][0][0][0]);

  for (int t0 = 0; t0 < kS; t0 += 8) {
    // stage x tile -> fp16 B layout (512 float2 loads, coalesced)
    if (tid < 512) {
      const int col = tid >> 5, sk2 = tid & 31;      // col = dt*2+c, k = sk2*2
      const int c = col & 1, dt = col >> 1;
      const float2 v = *reinterpret_cast<const float2*>(
          x + ((size_t)(b0 + c) * kS + (size_t)(t0 + dt)) * kI + sk2 * 2);
      const int k = sk2 * 2;
      *reinterpret_cast<unsigned*>(&xF[k >> 3][col][k & 7]) = packf2(v.x, v.y);
    }
    __syncthreads();

    // batched x-GEMM: xg[row][col] = Wx1[row,:] . x(col)
    {
      const char* xb = reinterpret_cast<const char*>(&xF[0][0][0]);
      f32x4 e0 = {0.f, 0.f, 0.f, 0.f}, e1 = {0.f, 0.f, 0.f, 0.f};
#pragma unroll
      for (int kt = 0; kt < 2; ++kt) {
        const f16x8 bf = *reinterpret_cast<const f16x8*>(
            xb + (((kt * 4 + q) * 16 + n) << 4));
        e0 = MFMA16(Ax[0][kt], bf, e0);
        e1 = MFMA16(Ax[1][kt], bf, e1);
      }
#pragma unroll
      for (int r = 0; r < 4; ++r) {
        xg[w * 32 + q * 4 + r][n]      = e0[r];
        xg[w * 32 + 16 + q * 4 + r][n] = e1[r];
      }
    }
    __syncthreads();

    for (int dt = 0; dt < 8; ++dt) {
      const int t = t0 + dt;
      const int rp = (t + 1) & 1;                    // parity holding h1(t-1)
      const char* hb = h1base + ((rp * 2 + csel) << 8);  // 256 B per (par,c)

      f32x4 d0 = {0.f, 0.f, 0.f, 0.f}, d1 = {0.f, 0.f, 0.f, 0.f};
      prio<1>();
#pragma unroll
      for (int kt = 0; kt < 4; ++kt) {
        const f16x8 bf = *reinterpret_cast<const f16x8*>(hb + ((kt * 4 + q) << 4));
        d0 = MFMA16(Ah[0][kt], bf, d0);
        d1 = MFMA16(Ah[1][kt], bf, d1);
      }
      prio<0>();

      if (n < 2) {
        *reinterpret_cast<f32x4*>(&gbuf[n][w * 32 + q * 4])      = d0;
        *reinterpret_cast<f32x4*>(&gbuf[n][w * 32 + 16 + q * 4]) = d1;
      }
      __syncthreads();

      if (tid < 256) {
        const int c = tid >> 7, j = tid & 127, col = dt * 2 + c;
        const float gi = xg[j][col]       + gbuf[c][j]       + bI;
        const float gf = xg[j + 128][col] + gbuf[c][j + 128] + bF;
        const float gg = xg[j + 256][col] + gbuf[c][j + 256] + bG;
        const float go = xg[j + 384][col] + gbuf[c][j + 384] + bO;
        cst = sigf(gf) * cst + sigf(gi) * tanhff(gg);
        const float h = sigf(go) * tanhff(cst);
        h1B[t & 1][c][j >> 3][j & 7] = (_Float16)h;
        h1out[((size_t)(b0 + c) * kS + (size_t)t) * kH + j] = (_Float16)h;
      }
      __syncthreads();
    }
  }
}

// ---------------- K2: layer-2, batched-h1 GEMM + recurrent MFMA + head -------
__global__ __launch_bounds__(1024) void lstm_l2(
    const _Float16* __restrict__ h1in,
    const float* __restrict__ Wx2, const float* __restrict__ bx2,
    const float* __restrict__ Wh2, const float* __restrict__ bh2,
    const float* __restrict__ Wc,  const float* __restrict__ bc,
    float* __restrict__ out)
{
  const int tid  = threadIdx.x;
  const int b0   = blockIdx.x * 2;
  const int w    = tid >> 6;
  const int lane = tid & 63;
  const int q    = lane >> 4;
  const int n    = lane & 15;

  __shared__ __align__(16) _Float16 h1F[16][16][8];    // [kc][col][e] 4 KiB
  __shared__ __align__(16) _Float16 h2B[2][2][16][8];  // 1 KiB
  __shared__ float xg[512][17];                        // 34 KiB h1-projection
  __shared__ float gbuf[2][512];                       // 4 KiB
  __shared__ float hfin[2][128];

  f16x8 Ax[2][4], Ah[2][4];            // 16 frags, 64 VGPR
  {
    const int rb = w * 32 + n;
#pragma unroll
    for (int s = 0; s < 2; ++s) {
      const int row = rb + s * 16;
#pragma unroll
      for (int kt = 0; kt < 4; ++kt) {
        Ax[s][kt] = afrag(Wx2, row, kt * 32 + q * 8, kH);
        Ah[s][kt] = afrag(Wh2, row, kt * 32 + q * 8, kH);
      }
    }
  }

  float bI = 0.f, bF = 0.f, bG = 0.f, bO = 0.f, cst = 0.f;
  if (tid < 256) {
    const int j = tid & 127;
    bI = bx2[j]       + bh2[j];
    bF = bx2[j + 128] + bh2[j + 128];
    bG = bx2[j + 256] + bh2[j + 256];
    bO = bx2[j + 384] + bh2[j + 384];
    reinterpret_cast<_Float16*>(&h2B[1][0][0][0])[tid] = (_Float16)0.f;  // h2(-1)=0
  }

  const int csel = (n < 2) ? n : 0;
  const char* h2base = reinterpret_cast<const char*>(&h2B[0][0][0][0]);

  for (int t0 = 0; t0 < kS; t0 += 8) {
    // stage h1 tile (1024 u32 copies, coalesced)
    {
      const int col = tid >> 6, sk2 = tid & 63;      // col = dt*2+c, k = sk2*2
      const int c = col & 1, dt = col >> 1;
      const unsigned v = *reinterpret_cast<const unsigned*>(
          h1in + ((size_t)(b0 + c) * kS + (size_t)(t0 + dt)) * kH + sk2 * 2);
      const int k = sk2 * 2;
      *reinterpret_cast<unsigned*>(&h1F[k >> 3][col][k & 7]) = v;
    }
    __syncthreads();

    // batched GEMM: xg[row][col] = Wx2[row,:] . h1(col)
    {
      const char* xb = reinterpret_cast<const char*>(&h1F[0][0][0]);
      f32x4 e0 = {0.f, 0.f, 0.f, 0.f}, e1 = {0.f, 0.f, 0.f, 0.f};
#pragma unroll
      for (int kt = 0; kt < 4; ++kt) {
        const f16x8 bf = *reinterpret_cast<const f16x8*>(
            xb + (((kt * 4 + q) * 16 + n) << 4));
        e0 = MFMA16(Ax[0][kt], bf, e0);
        e1 = MFMA16(Ax[1][kt], bf, e1);
      }
#pragma unroll
      for (int r = 0; r < 4; ++r) {
        xg[w * 32 + q * 4 + r][n]      = e0[r];
        xg[w * 32 + 16 + q * 4 + r][n] = e1[r];
      }
    }
    __syncthreads();

    for (int dt = 0; dt < 8; ++dt) {
      const int t = t0 + dt;
      const int rp = (t + 1) & 1;
      const char* hb = h2base + ((rp * 2 + csel) << 8);

      f32x4 d0 = {0.f, 0.f, 0.f, 0.f}, d1 = {0.f, 0.f, 0.f, 0.f};
      prio<1>();
#pragma unroll
      for (int kt = 0; kt < 4; ++kt) {
        const f16x8 bf = *reinterpret_cast<const f16x8*>(hb + ((kt * 4 + q) << 4));
        d0 = MFMA16(Ah[0][kt], bf, d0);
        d1 = MFMA16(Ah[1][kt], bf, d1);
      }
      prio<0>();

      if (n < 2) {
        *reinterpret_cast<f32x4*>(&gbuf[n][w * 32 + q * 4])      = d0;
        *reinterpret_cast<f32x4*>(&gbuf[n][w * 32 + 16 + q * 4]) = d1;
      }
      __syncthreads();

      if (tid < 256) {
        const int c = tid >> 7, j = tid & 127, col = dt * 2 + c;
        const float gi = xg[j][col]       + gbuf[c][j]       + bI;
        const float gf = xg[j + 128][col] + gbuf[c][j + 128] + bF;
        const float gg = xg[j + 256][col] + gbuf[c][j + 256] + bG;
        const float go = xg[j + 384][col] + gbuf[c][j + 384] + bO;
        cst = sigf(gf) * cst + sigf(gi) * tanhff(gg);
        const float h = sigf(go) * tanhff(cst);
        h2B[t & 1][c][j >> 3][j & 7] = (_Float16)h;
        if (t == kS - 1) hfin[c][j] = h;
      }
      __syncthreads();
    }
  }

  // classifier head: logits[b0+c, m] = Wc[m,:] . h2fin[c] + bc[m]
  if (tid < 8) {
    const int m = tid & 3, c = tid >> 2;
    const float* wr = Wc + (size_t)m * kH;
    float s0 = 0.f, s1 = 0.f, s2 = 0.f, s3 = 0.f;
#pragma unroll
    for (int j = 0; j < kH; j += 4) {
      s0 = fmaf(wr[j],     hfin[c][j],     s0);
      s1 = fmaf(wr[j + 1], hfin[c][j + 1], s1);
      s2 = fmaf(wr[j + 2], hfin[c][j + 2], s2);
      s3 = fmaf(wr[j + 3], hfin[c][j + 3], s3);
    }
    out[(size_t)(b0 + c) * 4 + m] = bc[m] + ((s0 + s1) + (s2 + s3));
  }
}

} // namespace

extern "C" void kernel_launch(void* const* d_in, const int* in_sizes, int n_in,
                              void* d_out, int out_size, void* d_ws, size_t ws_size,
                              hipStream_t stream) {
  const float* x   = (const float*)d_in[0];
  const float* Wx1 = (const float*)d_in[1];
  const float* bx1 = (const float*)d_in[2];
  const float* Wh1 = (const float*)d_in[3];
  const float* bh1 = (const float*)d_in[4];
  const float* Wx2 = (const float*)d_in[5];
  const float* bx2 = (const float*)d_in[6];
  const float* Wh2 = (const float*)d_in[7];
  const float* bh2 = (const float*)d_in[8];
  const float* Wc  = (const float*)d_in[9];
  const float* bc  = (const float*)d_in[10];

  _Float16* h1 = (_Float16*)d_ws;   // 512*1024*128 fp16 = 128 MiB layer-1 stream

  hipLaunchKernelGGL(lstm_l1, dim3(256), dim3(1024), 0, stream,
                     x, Wx1, bx1, Wh1, bh1, h1);
  hipLaunchKernelGGL(lstm_l2, dim3(256), dim3(1024), 0, stream,
                     h1, Wx2, bx2, Wh2, bh2, Wc, bc, (float*)d_out);
}